// Round 8
// baseline (239.112 us; speedup 1.0000x reference)
//
#include <hip/hip_runtime.h>

#define HRANGE 8192
#define DIM 64
#define RANK 16
#define CAP 64

// ---------------------------------------------------------------------------
// R8: one 256-thread block per nonempty bin (4 d-quarters fused; thread t ->
// d = (t>>6)*16 + ((t>>2)&15), q = t&3). Gathered rows (end_core in pass1,
// v1 in pass2) staged via ONE coalesced block-wide load into pad-striped LDS
// (double-buffered). Core row M stays per-lane (nt float4). v1 bf16 (32 MB).
// Launches: memset + bin + pass1 + pass2.
// ---------------------------------------------------------------------------

typedef float floatx4 __attribute__((ext_vector_type(4)));

__device__ __forceinline__ void fma4(float4& a, float s, const float4& m) {
    a.x = fmaf(s, m.x, a.x); a.y = fmaf(s, m.y, a.y);
    a.z = fmaf(s, m.z, a.z); a.w = fmaf(s, m.w, a.w);
}
__device__ __forceinline__ float4 ld4(const float* p) {
    return *reinterpret_cast<const float4*>(p);
}
__device__ __forceinline__ float4 ldnt4(const float* p) {
    floatx4 t = __builtin_nontemporal_load(reinterpret_cast<const floatx4*>(p));
    return make_float4(t.x, t.y, t.z, t.w);
}
__device__ __forceinline__ unsigned short f2bf(float x) {
    unsigned int u = __float_as_uint(x);
    u += 0x7FFFu + ((u >> 16) & 1u);          // RNE
    return (unsigned short)(u >> 16);
}
__device__ __forceinline__ float blo(unsigned int u) { return __uint_as_float(u << 16); }
__device__ __forceinline__ float bhi(unsigned int u) { return __uint_as_float(u & 0xFFFF0000u); }

// hist + fixed-cap lists + overflow + nonempty worklists
__global__ __launch_bounds__(256) void bin_kernel(const int* __restrict__ hs,
                                                  int* hist1, int* hist2,
                                                  int* ovfc, int* nec,
                                                  int* wl1, int* wl2,
                                                  int* list1, int* list2,
                                                  int* ovf1, int* ovf2, int B) {
    int b = blockIdx.x * blockDim.x + threadIdx.x;
    if (b >= B) return;
    int h1 = hs[b * 4 + 1];
    int s1 = atomicAdd(&hist1[h1], 1);
    if (s1 == 0) { int w = atomicAdd(&nec[0], 1); wl1[w] = h1; }
    if (s1 < CAP) list1[h1 * CAP + s1] = b;
    else { int o = atomicAdd(&ovfc[0], 1); ovf1[o] = b; }
    int h2 = hs[b * 4 + 2];
    int s2 = atomicAdd(&hist2[h2], 1);
    if (s2 == 0) { int w = atomicAdd(&nec[1], 1); wl2[w] = h2; }
    if (s2 < CAP) list2[h2 * CAP + s2] = b;
    else { int o = atomicAdd(&ovfc[1], 1); ovf2[o] = b; }
}

// pass1: v1[b][d][s] = sum_r cores0[h1[b]][d][r][s] * end_core[h3[b]][d][r]
__global__ __launch_bounds__(256) void pass1_kernel(const int* __restrict__ hs,
                                                    const float* __restrict__ end_core,
                                                    const float* __restrict__ cores0,
                                                    const int* __restrict__ hist1,
                                                    const int* __restrict__ list1,
                                                    const int* __restrict__ nec,
                                                    const int* __restrict__ wl1,
                                                    const int* __restrict__ ovfc,
                                                    const int* __restrict__ ovf1,
                                                    unsigned short* __restrict__ v1) {
    const int t = threadIdx.x;
    const int dl = (t >> 2) & 15, q = t & 3, w = t >> 6;
    const int d = w * 16 + dl;
    const int bid = blockIdx.x;

    if (bid < HRANGE) {
        if (bid >= nec[0]) return;
        const int h = wl1[bid];

        const float* Mrow = cores0 + ((size_t)h * DIM + d) * (RANK * RANK) + q * 4;
        float4 M[16];
        #pragma unroll
        for (int r = 0; r < 16; ++r) M[r] = ldnt4(Mrow + r * RANK);

        const int cnt = hist1[h];
        const int n = cnt < CAP ? cnt : CAP;

        __shared__ int sb[CAP], sh[CAP];
        __shared__ float ebuf[2][1280];          // 64 d x 16 r, stride 20 (pad)
        if (t < n) {
            int b = list1[h * CAP + t];
            sb[t] = b;
            sh[t] = hs[b * 4 + 3];
        }
        __syncthreads();

        // stage row 0: one coalesced block-wide load (256 x 16B = 4KB row)
        {
            const float* e = end_core + (size_t)sh[0] * (DIM * RANK);
            *reinterpret_cast<float4*>(&ebuf[0][(t >> 2) * 20 + (t & 3) * 4]) = ld4(e + t * 4);
        }
        for (int i = 0; i < n; ++i) {
            __syncthreads();                     // ebuf[i&1] ready; other buf free
            if (i + 1 < n) {                     // prefetch row i+1 into other buf
                const float* e = end_core + (size_t)sh[i + 1] * (DIM * RANK);
                *reinterpret_cast<float4*>(&ebuf[(i + 1) & 1][(t >> 2) * 20 + (t & 3) * 4]) = ld4(e + t * 4);
            }
            const float* eb = &ebuf[i & 1][d * 20];
            float4 c0 = ld4(eb), c1 = ld4(eb + 4), c2 = ld4(eb + 8), c3 = ld4(eb + 12);
            float4 acc = make_float4(0.f, 0.f, 0.f, 0.f);
            fma4(acc, c0.x, M[0]);  fma4(acc, c0.y, M[1]);
            fma4(acc, c0.z, M[2]);  fma4(acc, c0.w, M[3]);
            fma4(acc, c1.x, M[4]);  fma4(acc, c1.y, M[5]);
            fma4(acc, c1.z, M[6]);  fma4(acc, c1.w, M[7]);
            fma4(acc, c2.x, M[8]);  fma4(acc, c2.y, M[9]);
            fma4(acc, c2.z, M[10]); fma4(acc, c2.w, M[11]);
            fma4(acc, c3.x, M[12]); fma4(acc, c3.y, M[13]);
            fma4(acc, c3.z, M[14]); fma4(acc, c3.w, M[15]);
            *reinterpret_cast<ushort4*>(v1 + (size_t)sb[i] * (DIM * RANK) + d * RANK + q * 4) =
                make_ushort4(f2bf(acc.x), f2bf(acc.y), f2bf(acc.z), f2bf(acc.w));
        }
    } else {
        // overflow entries (expected ~0)
        const int no = ovfc[0];
        for (int i = 0; i < no; ++i) {
            int b = ovf1[i];
            int h = hs[b * 4 + 1], h3 = hs[b * 4 + 3];
            const float* Mr = cores0 + ((size_t)h * DIM + d) * (RANK * RANK) + q * 4;
            const float* e = end_core + ((size_t)h3 * DIM + d) * RANK;
            float4 e0 = ld4(e), e1 = ld4(e + 4), e2 = ld4(e + 8), e3 = ld4(e + 12);
            const float ev[16] = {e0.x, e0.y, e0.z, e0.w, e1.x, e1.y, e1.z, e1.w,
                                  e2.x, e2.y, e2.z, e2.w, e3.x, e3.y, e3.z, e3.w};
            float4 acc = make_float4(0.f, 0.f, 0.f, 0.f);
            #pragma unroll
            for (int r = 0; r < 16; ++r) fma4(acc, ev[r], ld4(Mr + r * RANK));
            *reinterpret_cast<ushort4*>(v1 + (size_t)b * (DIM * RANK) + d * RANK + q * 4) =
                make_ushort4(f2bf(acc.x), f2bf(acc.y), f2bf(acc.z), f2bf(acc.w));
        }
    }
}

// pass2: out[b][d] = dot(start_core[h0[b]][d], sum_r cores1[h2[b]][d][r][:] * v1[b][d][r])
__global__ __launch_bounds__(256) void pass2_kernel(const int* __restrict__ hs,
                                                    const float* __restrict__ start_core,
                                                    const float* __restrict__ cores1,
                                                    const int* __restrict__ hist2,
                                                    const int* __restrict__ list2,
                                                    const int* __restrict__ nec,
                                                    const int* __restrict__ wl2,
                                                    const int* __restrict__ ovfc,
                                                    const int* __restrict__ ovf2,
                                                    const unsigned short* __restrict__ v1,
                                                    float* __restrict__ out) {
    const int t = threadIdx.x;
    const int dl = (t >> 2) & 15, q = t & 3, w = t >> 6;
    const int d = w * 16 + dl;
    const int bid = blockIdx.x;

    if (bid < HRANGE) {
        if (bid >= nec[0]) return;
        const int h = wl2[bid];

        const float* Mrow = cores1 + ((size_t)h * DIM + d) * (RANK * RANK) + q * 4;
        float4 M[16];
        #pragma unroll
        for (int r = 0; r < 16; ++r) M[r] = ldnt4(Mrow + r * RANK);

        const int cnt = hist2[h];
        const int n = cnt < CAP ? cnt : CAP;

        __shared__ int sb[CAP], sh0[CAP];
        __shared__ unsigned int vbuf[2][768];    // 64 d x 8 uints, stride 12 (pad)
        if (t < n) {
            int b = list2[h * CAP + t];
            sb[t] = b;
            sh0[t] = hs[b * 4 + 0];
        }
        __syncthreads();

        // stage v1 row 0: one coalesced block-wide load (256 x 8B = 2KB row)
        {
            const unsigned int* vr = reinterpret_cast<const unsigned int*>(
                v1 + (size_t)sb[0] * (DIM * RANK));
            *reinterpret_cast<uint2*>(&vbuf[0][(t >> 2) * 12 + (t & 3) * 2]) =
                *reinterpret_cast<const uint2*>(vr + t * 2);
        }
        float4 nsc = ld4(start_core + (size_t)sh0[0] * (DIM * RANK) + t * 4);
        for (int i = 0; i < n; ++i) {
            __syncthreads();
            if (i + 1 < n) {
                const unsigned int* vr = reinterpret_cast<const unsigned int*>(
                    v1 + (size_t)sb[i + 1] * (DIM * RANK));
                *reinterpret_cast<uint2*>(&vbuf[(i + 1) & 1][(t >> 2) * 12 + (t & 3) * 2]) =
                    *reinterpret_cast<const uint2*>(vr + t * 2);
            }
            float4 sc = nsc;
            if (i + 1 < n)
                nsc = ld4(start_core + (size_t)sh0[i + 1] * (DIM * RANK) + t * 4);

            const unsigned int* vb = &vbuf[i & 1][d * 12];
            uint4 a  = *reinterpret_cast<const uint4*>(vb);
            uint4 bb = *reinterpret_cast<const uint4*>(vb + 4);
            float4 c0 = make_float4(blo(a.x),  bhi(a.x),  blo(a.y),  bhi(a.y));
            float4 c1 = make_float4(blo(a.z),  bhi(a.z),  blo(a.w),  bhi(a.w));
            float4 c2 = make_float4(blo(bb.x), bhi(bb.x), blo(bb.y), bhi(bb.y));
            float4 c3 = make_float4(blo(bb.z), bhi(bb.z), blo(bb.w), bhi(bb.w));
            float4 acc = make_float4(0.f, 0.f, 0.f, 0.f);
            fma4(acc, c0.x, M[0]);  fma4(acc, c0.y, M[1]);
            fma4(acc, c0.z, M[2]);  fma4(acc, c0.w, M[3]);
            fma4(acc, c1.x, M[4]);  fma4(acc, c1.y, M[5]);
            fma4(acc, c1.z, M[6]);  fma4(acc, c1.w, M[7]);
            fma4(acc, c2.x, M[8]);  fma4(acc, c2.y, M[9]);
            fma4(acc, c2.z, M[10]); fma4(acc, c2.w, M[11]);
            fma4(acc, c3.x, M[12]); fma4(acc, c3.y, M[13]);
            fma4(acc, c3.z, M[14]); fma4(acc, c3.w, M[15]);
            float partial = acc.x * sc.x + acc.y * sc.y + acc.z * sc.z + acc.w * sc.w;
            partial += __shfl_xor(partial, 1);
            partial += __shfl_xor(partial, 2);
            if (q == 0) out[(size_t)sb[i] * DIM + d] = partial;
        }
    } else {
        const int no = ovfc[0];
        for (int i = 0; i < no; ++i) {
            int b = ovf2[i];
            int h = hs[b * 4 + 2], h0 = hs[b * 4 + 0];
            const float* Mr = cores1 + ((size_t)h * DIM + d) * (RANK * RANK) + q * 4;
            const unsigned short* vv = v1 + (size_t)b * (DIM * RANK) + d * RANK;
            uint4 a  = *reinterpret_cast<const uint4*>(vv);
            uint4 bb = *reinterpret_cast<const uint4*>(vv + 8);
            const float ev[16] = {blo(a.x),  bhi(a.x),  blo(a.y),  bhi(a.y),
                                  blo(a.z),  bhi(a.z),  blo(a.w),  bhi(a.w),
                                  blo(bb.x), bhi(bb.x), blo(bb.y), bhi(bb.y),
                                  blo(bb.z), bhi(bb.z), blo(bb.w), bhi(bb.w)};
            float4 acc = make_float4(0.f, 0.f, 0.f, 0.f);
            #pragma unroll
            for (int r = 0; r < 16; ++r) fma4(acc, ev[r], ld4(Mr + r * RANK));
            float4 sc = ld4(start_core + ((size_t)h0 * DIM + d) * RANK + q * 4);
            float partial = acc.x * sc.x + acc.y * sc.y + acc.z * sc.z + acc.w * sc.w;
            partial += __shfl_xor(partial, 1);
            partial += __shfl_xor(partial, 2);
            if (q == 0) out[(size_t)b * DIM + d] = partial;
        }
    }
}

extern "C" void kernel_launch(void* const* d_in, const int* in_sizes, int n_in,
                              void* d_out, int out_size, void* d_ws, size_t ws_size,
                              hipStream_t stream) {
    const int*   hs         = (const int*)d_in[0];
    const float* start_core = (const float*)d_in[1];
    const float* end_core   = (const float*)d_in[2];
    const float* cores      = (const float*)d_in[3];
    float*       out        = (float*)d_out;
    const int B = in_sizes[0] / 4;

    // workspace: v1 (bf16, 32 MB, 16B-aligned) then int arrays
    unsigned short* v1 = (unsigned short*)d_ws;       // B*DIM*RANK ushorts
    int* hist1 = (int*)(v1 + (size_t)B * DIM * RANK);
    int* hist2 = hist1 + HRANGE;
    int* ovfc  = hist2 + HRANGE;                      // 2
    int* nec   = ovfc + 2;                            // 2
    int* wl1   = nec + 2;
    int* wl2   = wl1 + HRANGE;
    int* list1 = wl2 + HRANGE;
    int* list2 = list1 + HRANGE * CAP;
    int* ovf1  = list2 + HRANGE * CAP;
    int* ovf2  = ovf1 + B;

    hipMemsetAsync(hist1, 0, (2 * HRANGE + 4) * sizeof(int), stream);
    bin_kernel<<<(B + 255) / 256, 256, 0, stream>>>(hs, hist1, hist2, ovfc, nec,
                                                    wl1, wl2, list1, list2, ovf1, ovf2, B);
    pass1_kernel<<<HRANGE + 1, 256, 0, stream>>>(hs, end_core, cores,
                                                 hist1, list1, nec, wl1, ovfc, ovf1, v1);
    pass2_kernel<<<HRANGE + 1, 256, 0, stream>>>(hs, start_core,
                                                 cores + (size_t)HRANGE * DIM * RANK * RANK,
                                                 hist2, list2, nec + 1, wl2, ovfc + 1, ovf2,
                                                 v1, out);
}

// Round 9
// 232.828 us; speedup vs baseline: 1.0270x; 1.0270x over previous
//
#include <hip/hip_runtime.h>

#define HRANGE 8192
#define DIM 64
#define RANK 16
#define CAP 64

// ---------------------------------------------------------------------------
// R9: R7 structure (one-wave block per (nonempty bin, d-quarter)) minus LDS:
// bin lists held in registers (lane i owns item i, broadcast by __shfl),
// no __syncthreads, 2-deep register prefetch of the per-item gathers.
// Core row M per-lane via nontemporal float4. v1 bf16 (32 MB, L3-resident).
// ---------------------------------------------------------------------------

typedef float floatx4 __attribute__((ext_vector_type(4)));

__device__ __forceinline__ void fma4(float4& a, float s, const float4& m) {
    a.x = fmaf(s, m.x, a.x); a.y = fmaf(s, m.y, a.y);
    a.z = fmaf(s, m.z, a.z); a.w = fmaf(s, m.w, a.w);
}
__device__ __forceinline__ float4 ld4(const float* p) {
    return *reinterpret_cast<const float4*>(p);
}
__device__ __forceinline__ float4 ldnt4(const float* p) {
    floatx4 t = __builtin_nontemporal_load(reinterpret_cast<const floatx4*>(p));
    return make_float4(t.x, t.y, t.z, t.w);
}
__device__ __forceinline__ unsigned short f2bf(float x) {
    unsigned int u = __float_as_uint(x);
    u += 0x7FFFu + ((u >> 16) & 1u);          // RNE
    return (unsigned short)(u >> 16);
}
__device__ __forceinline__ float blo(unsigned int u) { return __uint_as_float(u << 16); }
__device__ __forceinline__ float bhi(unsigned int u) { return __uint_as_float(u & 0xFFFF0000u); }

// hist + fixed-cap lists + overflow + nonempty worklists
__global__ __launch_bounds__(256) void bin_kernel(const int* __restrict__ hs,
                                                  int* hist1, int* hist2,
                                                  int* ovfc, int* nec,
                                                  int* wl1, int* wl2,
                                                  int* list1, int* list2,
                                                  int* ovf1, int* ovf2, int B) {
    int b = blockIdx.x * blockDim.x + threadIdx.x;
    if (b >= B) return;
    int h1 = hs[b * 4 + 1];
    int s1 = atomicAdd(&hist1[h1], 1);
    if (s1 == 0) { int w = atomicAdd(&nec[0], 1); wl1[w] = h1; }
    if (s1 < CAP) list1[h1 * CAP + s1] = b;
    else { int o = atomicAdd(&ovfc[0], 1); ovf1[o] = b; }
    int h2 = hs[b * 4 + 2];
    int s2 = atomicAdd(&hist2[h2], 1);
    if (s2 == 0) { int w = atomicAdd(&nec[1], 1); wl2[w] = h2; }
    if (s2 < CAP) list2[h2 * CAP + s2] = b;
    else { int o = atomicAdd(&ovfc[1], 1); ovf2[o] = b; }
}

// pass1: v1[b][d][s] = sum_r cores0[h1[b]][d][r][s] * end_core[h3[b]][d][r]
__global__ __launch_bounds__(64) void pass1_kernel(const int* __restrict__ hs,
                                                   const float* __restrict__ end_core,
                                                   const float* __restrict__ cores0,
                                                   const int* __restrict__ hist1,
                                                   const int* __restrict__ list1,
                                                   const int* __restrict__ nec,
                                                   const int* __restrict__ wl1,
                                                   const int* __restrict__ ovfc,
                                                   const int* __restrict__ ovf1,
                                                   unsigned short* __restrict__ v1) {
    const int lane = threadIdx.x;
    const int dl = lane >> 2, q = lane & 3;
    const int bid = blockIdx.x;

    if (bid < HRANGE * 4) {
        const int widx = bid >> 2;
        if (widx >= nec[0]) return;
        const int h = wl1[widx];
        const int d = (bid & 3) * 16 + dl;

        const int cnt = hist1[h];
        const int n = cnt < CAP ? cnt : CAP;

        // register-resident bin list: lane i owns item i
        int breg = 0, hreg = 0;
        if (lane < n) {
            breg = list1[h * CAP + lane];
            hreg = hs[breg * 4 + 3];
        }

        const float* Mrow = cores0 + ((size_t)h * DIM + d) * (RANK * RANK) + q * 4;
        float4 M[16];
        #pragma unroll
        for (int r = 0; r < 16; ++r) M[r] = ldnt4(Mrow + r * RANK);

        // 2-deep prefetch of per-item end_core rows
        float4 a0, a1, a2, a3, b0, b1, b2, b3;
        {
            const float* e = end_core + ((size_t)__shfl(hreg, 0) * DIM + d) * RANK;
            a0 = ld4(e); a1 = ld4(e + 4); a2 = ld4(e + 8); a3 = ld4(e + 12);
        }
        if (n > 1) {
            const float* e = end_core + ((size_t)__shfl(hreg, 1) * DIM + d) * RANK;
            b0 = ld4(e); b1 = ld4(e + 4); b2 = ld4(e + 8); b3 = ld4(e + 12);
        }
        for (int i = 0; i < n; ++i) {
            float4 c0, c1, c2, c3;
            if (i & 1) { c0 = b0; c1 = b1; c2 = b2; c3 = b3; }
            else       { c0 = a0; c1 = a1; c2 = a2; c3 = a3; }
            if (i + 2 < n) {   // refill the slot just consumed (same parity)
                const float* e = end_core + ((size_t)__shfl(hreg, i + 2) * DIM + d) * RANK;
                if (i & 1) { b0 = ld4(e); b1 = ld4(e + 4); b2 = ld4(e + 8); b3 = ld4(e + 12); }
                else       { a0 = ld4(e); a1 = ld4(e + 4); a2 = ld4(e + 8); a3 = ld4(e + 12); }
            }
            float4 acc = make_float4(0.f, 0.f, 0.f, 0.f);
            fma4(acc, c0.x, M[0]);  fma4(acc, c0.y, M[1]);
            fma4(acc, c0.z, M[2]);  fma4(acc, c0.w, M[3]);
            fma4(acc, c1.x, M[4]);  fma4(acc, c1.y, M[5]);
            fma4(acc, c1.z, M[6]);  fma4(acc, c1.w, M[7]);
            fma4(acc, c2.x, M[8]);  fma4(acc, c2.y, M[9]);
            fma4(acc, c2.z, M[10]); fma4(acc, c2.w, M[11]);
            fma4(acc, c3.x, M[12]); fma4(acc, c3.y, M[13]);
            fma4(acc, c3.z, M[14]); fma4(acc, c3.w, M[15]);
            const int bcur = __shfl(breg, i);
            *reinterpret_cast<ushort4*>(v1 + (size_t)bcur * (DIM * RANK) + d * RANK + q * 4) =
                make_ushort4(f2bf(acc.x), f2bf(acc.y), f2bf(acc.z), f2bf(acc.w));
        }
    } else {
        // overflow entries (expected ~0)
        const int d = (bid - HRANGE * 4) * 16 + dl;
        const int no = ovfc[0];
        for (int i = 0; i < no; ++i) {
            int b = ovf1[i];
            int h = hs[b * 4 + 1], h3 = hs[b * 4 + 3];
            const float* Mr = cores0 + ((size_t)h * DIM + d) * (RANK * RANK) + q * 4;
            const float* e = end_core + ((size_t)h3 * DIM + d) * RANK;
            float4 e0 = ld4(e), e1 = ld4(e + 4), e2 = ld4(e + 8), e3 = ld4(e + 12);
            const float ev[16] = {e0.x, e0.y, e0.z, e0.w, e1.x, e1.y, e1.z, e1.w,
                                  e2.x, e2.y, e2.z, e2.w, e3.x, e3.y, e3.z, e3.w};
            float4 acc = make_float4(0.f, 0.f, 0.f, 0.f);
            #pragma unroll
            for (int r = 0; r < 16; ++r) fma4(acc, ev[r], ld4(Mr + r * RANK));
            *reinterpret_cast<ushort4*>(v1 + (size_t)b * (DIM * RANK) + d * RANK + q * 4) =
                make_ushort4(f2bf(acc.x), f2bf(acc.y), f2bf(acc.z), f2bf(acc.w));
        }
    }
}

// pass2: out[b][d] = dot(start_core[h0[b]][d], sum_r cores1[h2[b]][d][r][:] * v1[b][d][r])
__global__ __launch_bounds__(64) void pass2_kernel(const int* __restrict__ hs,
                                                   const float* __restrict__ start_core,
                                                   const float* __restrict__ cores1,
                                                   const int* __restrict__ hist2,
                                                   const int* __restrict__ list2,
                                                   const int* __restrict__ nec,
                                                   const int* __restrict__ wl2,
                                                   const int* __restrict__ ovfc,
                                                   const int* __restrict__ ovf2,
                                                   const unsigned short* __restrict__ v1,
                                                   float* __restrict__ out) {
    const int lane = threadIdx.x;
    const int dl = lane >> 2, q = lane & 3;
    const int bid = blockIdx.x;

    if (bid < HRANGE * 4) {
        const int widx = bid >> 2;
        if (widx >= nec[0]) return;
        const int h = wl2[widx];
        const int d = (bid & 3) * 16 + dl;

        const int cnt = hist2[h];
        const int n = cnt < CAP ? cnt : CAP;

        int breg = 0, hreg = 0;
        if (lane < n) {
            breg = list2[h * CAP + lane];
            hreg = hs[breg * 4 + 0];
        }

        const float* Mrow = cores1 + ((size_t)h * DIM + d) * (RANK * RANK) + q * 4;
        float4 M[16];
        #pragma unroll
        for (int r = 0; r < 16; ++r) M[r] = ldnt4(Mrow + r * RANK);

        // 2-deep prefetch: v1 row (2x uint4) + start_core quad
        uint4 ua0, ua1, ub0, ub1; float4 sca, scb;
        {
            const unsigned short* vv = v1 + (size_t)__shfl(breg, 0) * (DIM * RANK) + d * RANK;
            ua0 = *reinterpret_cast<const uint4*>(vv);
            ua1 = *reinterpret_cast<const uint4*>(vv + 8);
            sca = ld4(start_core + ((size_t)__shfl(hreg, 0) * DIM + d) * RANK + q * 4);
        }
        if (n > 1) {
            const unsigned short* vv = v1 + (size_t)__shfl(breg, 1) * (DIM * RANK) + d * RANK;
            ub0 = *reinterpret_cast<const uint4*>(vv);
            ub1 = *reinterpret_cast<const uint4*>(vv + 8);
            scb = ld4(start_core + ((size_t)__shfl(hreg, 1) * DIM + d) * RANK + q * 4);
        }
        for (int i = 0; i < n; ++i) {
            uint4 a, bb; float4 sc;
            if (i & 1) { a = ub0; bb = ub1; sc = scb; }
            else       { a = ua0; bb = ua1; sc = sca; }
            if (i + 2 < n) {
                const unsigned short* vv = v1 + (size_t)__shfl(breg, i + 2) * (DIM * RANK) + d * RANK;
                float4 s2 = ld4(start_core + ((size_t)__shfl(hreg, i + 2) * DIM + d) * RANK + q * 4);
                if (i & 1) { ub0 = *reinterpret_cast<const uint4*>(vv);
                             ub1 = *reinterpret_cast<const uint4*>(vv + 8); scb = s2; }
                else       { ua0 = *reinterpret_cast<const uint4*>(vv);
                             ua1 = *reinterpret_cast<const uint4*>(vv + 8); sca = s2; }
            }
            float4 c0 = make_float4(blo(a.x),  bhi(a.x),  blo(a.y),  bhi(a.y));
            float4 c1 = make_float4(blo(a.z),  bhi(a.z),  blo(a.w),  bhi(a.w));
            float4 c2 = make_float4(blo(bb.x), bhi(bb.x), blo(bb.y), bhi(bb.y));
            float4 c3 = make_float4(blo(bb.z), bhi(bb.z), blo(bb.w), bhi(bb.w));
            float4 acc = make_float4(0.f, 0.f, 0.f, 0.f);
            fma4(acc, c0.x, M[0]);  fma4(acc, c0.y, M[1]);
            fma4(acc, c0.z, M[2]);  fma4(acc, c0.w, M[3]);
            fma4(acc, c1.x, M[4]);  fma4(acc, c1.y, M[5]);
            fma4(acc, c1.z, M[6]);  fma4(acc, c1.w, M[7]);
            fma4(acc, c2.x, M[8]);  fma4(acc, c2.y, M[9]);
            fma4(acc, c2.z, M[10]); fma4(acc, c2.w, M[11]);
            fma4(acc, c3.x, M[12]); fma4(acc, c3.y, M[13]);
            fma4(acc, c3.z, M[14]); fma4(acc, c3.w, M[15]);
            float partial = acc.x * sc.x + acc.y * sc.y + acc.z * sc.z + acc.w * sc.w;
            partial += __shfl_xor(partial, 1);
            partial += __shfl_xor(partial, 2);
            const int bcur = __shfl(breg, i);
            if (q == 0) out[(size_t)bcur * DIM + d] = partial;
        }
    } else {
        const int d = (bid - HRANGE * 4) * 16 + dl;
        const int no = ovfc[0];
        for (int i = 0; i < no; ++i) {
            int b = ovf2[i];
            int h = hs[b * 4 + 2], h0 = hs[b * 4 + 0];
            const float* Mr = cores1 + ((size_t)h * DIM + d) * (RANK * RANK) + q * 4;
            const unsigned short* vv = v1 + (size_t)b * (DIM * RANK) + d * RANK;
            uint4 a  = *reinterpret_cast<const uint4*>(vv);
            uint4 bb = *reinterpret_cast<const uint4*>(vv + 8);
            const float ev[16] = {blo(a.x),  bhi(a.x),  blo(a.y),  bhi(a.y),
                                  blo(a.z),  bhi(a.z),  blo(a.w),  bhi(a.w),
                                  blo(bb.x), bhi(bb.x), blo(bb.y), bhi(bb.y),
                                  blo(bb.z), bhi(bb.z), blo(bb.w), bhi(bb.w)};
            float4 acc = make_float4(0.f, 0.f, 0.f, 0.f);
            #pragma unroll
            for (int r = 0; r < 16; ++r) fma4(acc, ev[r], ld4(Mr + r * RANK));
            float4 sc = ld4(start_core + ((size_t)h0 * DIM + d) * RANK + q * 4);
            float partial = acc.x * sc.x + acc.y * sc.y + acc.z * sc.z + acc.w * sc.w;
            partial += __shfl_xor(partial, 1);
            partial += __shfl_xor(partial, 2);
            if (q == 0) out[(size_t)b * DIM + d] = partial;
        }
    }
}

extern "C" void kernel_launch(void* const* d_in, const int* in_sizes, int n_in,
                              void* d_out, int out_size, void* d_ws, size_t ws_size,
                              hipStream_t stream) {
    const int*   hs         = (const int*)d_in[0];
    const float* start_core = (const float*)d_in[1];
    const float* end_core   = (const float*)d_in[2];
    const float* cores      = (const float*)d_in[3];
    float*       out        = (float*)d_out;
    const int B = in_sizes[0] / 4;

    // workspace: v1 (bf16, 32 MB, 16B-aligned) then int arrays
    unsigned short* v1 = (unsigned short*)d_ws;       // B*DIM*RANK ushorts
    int* hist1 = (int*)(v1 + (size_t)B * DIM * RANK);
    int* hist2 = hist1 + HRANGE;
    int* ovfc  = hist2 + HRANGE;                      // 2
    int* nec   = ovfc + 2;                            // 2
    int* wl1   = nec + 2;
    int* wl2   = wl1 + HRANGE;
    int* list1 = wl2 + HRANGE;
    int* list2 = list1 + HRANGE * CAP;
    int* ovf1  = list2 + HRANGE * CAP;
    int* ovf2  = ovf1 + B;

    hipMemsetAsync(hist1, 0, (2 * HRANGE + 4) * sizeof(int), stream);
    bin_kernel<<<(B + 255) / 256, 256, 0, stream>>>(hs, hist1, hist2, ovfc, nec,
                                                    wl1, wl2, list1, list2, ovf1, ovf2, B);
    pass1_kernel<<<HRANGE * 4 + 4, 64, 0, stream>>>(hs, end_core, cores,
                                                    hist1, list1, nec, wl1, ovfc, ovf1, v1);
    pass2_kernel<<<HRANGE * 4 + 4, 64, 0, stream>>>(hs, start_core,
                                                    cores + (size_t)HRANGE * DIM * RANK * RANK,
                                                    hist2, list2, nec + 1, wl2, ovfc + 1, ovf2,
                                                    v1, out);
}